// Round 17
// baseline (131.779 us; speedup 1.0000x reference)
//
#include <hip/hip_runtime.h>
#include <math.h>

// Problem constants
#define BB 256
#define NE 400
#define NP (BB * NE)        // 102400 pairs
#define HID 256
#define NCOP 224
#define DIN 480
#define MBLK 64             // pairs per block in fused MFMA kernel
#define NBLK (NP / MBLK)    // 1600

typedef _Float16 half8 __attribute__((ext_vector_type(8)));
typedef _Float16 half4 __attribute__((ext_vector_type(4)));
typedef float f4 __attribute__((ext_vector_type(4)));

// Native silu: v_mul + v_exp_f32 + v_add + v_rcp_f32 + v_mul (round 13: -12 us).
static __device__ __forceinline__ float silu_f(float x) {
    float e = __builtin_amdgcn_exp2f(x * -1.44269504088896340736f);
    return x * __builtin_amdgcn_rcpf(1.0f + e);
}

// Swizzled byte offset into the activation LDS buffer.
static __device__ __forceinline__ int swz(int row, int colbyte) {
    return (row * 512 + colbyte) ^ ((row & 7) << 4);
}

// ---------------------------------------------------------------------------
// Precompute (fp32): E1/F1/Fo/S as before.
// ---------------------------------------------------------------------------
__global__ void precompute_kernel(const float* __restrict__ h_abs,
                                  const float* __restrict__ e_feat,
                                  const float* __restrict__ field,
                                  const float* __restrict__ mW1,
                                  const float* __restrict__ mb1,
                                  const float* __restrict__ oW1,
                                  const float* __restrict__ ob1,
                                  float* __restrict__ E1,
                                  float* __restrict__ F1,
                                  float* __restrict__ Fo,
                                  float* __restrict__ S)
{
    int r = blockIdx.x;
    int t = threadIdx.x;
    if (r < NE) {
        float a = 0.f;
        #pragma unroll
        for (int k = 0; k < 32; ++k) a += e_feat[r * 32 + k] * mW1[k * HID + t];
        E1[r * HID + t] = a;
    } else if (r < NE + BB) {
        int b = r - NE;
        float a = mb1[t];
        #pragma unroll
        for (int k = 0; k < 64; ++k) a += field[b * 64 + k] * mW1[(32 + k) * HID + t];
        F1[b * HID + t] = a;
    } else if (r < NE + 2 * BB) {
        int b = r - NE - BB;
        float a = ob1[t];
        #pragma unroll
        for (int k = 0; k < 64; ++k) a += field[b * 64 + k] * oW1[(224 + k) * HID + t];
        Fo[b * HID + t] = a;
    } else {
        int b = r - NE - 2 * BB;
        if (t < 64) {
            const float* x = h_abs + b * DIN + 128 + t * 3;
            S[b * 96 + t] = (x[0]*x[0] + x[1]*x[1] + x[2]*x[2]) * (1.0f / 3.0f);
        } else if (t < 96) {
            int c = t - 64;
            const float* x = h_abs + b * DIN + 320 + c * 5;
            float s = 0.f;
            #pragma unroll
            for (int d = 0; d < 5; ++d) s += x[d] * x[d];
            S[b * 96 + t] = s * 0.2f;
        }
    }
}

// ---------------------------------------------------------------------------
// Pack weights (fp32 -> fp16) into MFMA A-operand fragment order.
// ---------------------------------------------------------------------------
__global__ void pack_weights(const float* __restrict__ mW2, const float* __restrict__ mW3,
                             const float* __restrict__ oW1, const float* __restrict__ oW2,
                             _Float16* __restrict__ PB2, _Float16* __restrict__ PB3,
                             _Float16* __restrict__ PO1, _Float16* __restrict__ PO2)
{
    int blk = blockIdx.x;
    int l = threadIdx.x;
    const float* W; _Float16* P; int LD;
    if (blk < 128)      { W = mW2; P = PB2; LD = 256; }
    else if (blk < 240) { blk -= 128; W = mW3; P = PB3; LD = 224; }
    else if (blk < 352) { blk -= 240; W = oW1; P = PO1; LD = 256; }
    else                { blk -= 352; W = oW2; P = PO2; LD = 256; }
    int KST = (P == PO1) ? 7 : 8;
    int nt = blk / KST, ks = blk - nt * KST;
    int n  = nt * 16 + (l & 15);
    int k0 = ks * 32 + (l >> 4) * 8;
    half8 v;
    #pragma unroll
    for (int j = 0; j < 8; ++j) v[j] = (_Float16)W[(size_t)(k0 + j) * LD + n];
    *(half8*)&P[(size_t)(blk * 64 + l) * 8] = v;
}

// ---------------------------------------------------------------------------
// Row-split GEMM phase: wave (wh, wc) computes rows [wh*32, wh*32+32) for
// NT n-tiles {wc, wc+4, wc+8, (wc+12)}. Each wave reads only its 32 rows of
// act (16 KB/phase, half of the previous 8-way-column split's 32 KB).
// Weight fragments hoisted; acc caller-initialized (bias folded into C-in).
// ---------------------------------------------------------------------------
template<int KST, int NT>
static __device__ __forceinline__ void mma_phase4(const half8* __restrict__ Wp,
                                                  const char* actp, int lane,
                                                  int wh, int wc, f4 acc[4][2])
{
    half8 bf[NT][KST];
    #pragma unroll
    for (int ti = 0; ti < NT; ++ti)
        #pragma unroll
        for (int ks = 0; ks < KST; ++ks)
            bf[ti][ks] = Wp[((wc + ti * 4) * KST + ks) * 64 + lane];

    #pragma unroll
    for (int ks = 0; ks < KST; ++ks) {
        int kb = ks * 64 + ((lane >> 4) << 4);
        half8 a[2];
        #pragma unroll
        for (int mt = 0; mt < 2; ++mt) {
            int row = wh * 32 + mt * 16 + (lane & 15);
            a[mt] = *(const half8*)(actp + ((row * 512 + kb) ^ ((row & 7) << 4)));
        }
        #pragma unroll
        for (int ti = 0; ti < NT; ++ti)
            #pragma unroll
            for (int mt = 0; mt < 2; ++mt)
                acc[ti][mt] = __builtin_amdgcn_mfma_f32_16x16x32_f16(bf[ti][ks], a[mt], acc[ti][mt], 0, 0, 0);
    }
}

// ---------------------------------------------------------------------------
// Fused kernel: 64 pairs / block, 512 threads (8 waves = 2 row-halves x 4
// column-waves). Single 32 KB act buffer; E+F in-register; bias-folded acc.
// ---------------------------------------------------------------------------
__global__ __launch_bounds__(512, 1)
void fused_mfma(const float* __restrict__ h_abs,
                const float* __restrict__ mb2, const float* __restrict__ mb3,
                const float* __restrict__ ob2,
                const float* __restrict__ oW3, const float* __restrict__ ob3,
                const float* __restrict__ E1, const float* __restrict__ F1,
                const float* __restrict__ Fo, const float* __restrict__ S,
                const half8* __restrict__ PB2, const half8* __restrict__ PB3,
                const half8* __restrict__ PO1, const half8* __restrict__ PO2,
                float* __restrict__ out)
{
    __shared__ char act[MBLK * 512];   // 32 KB f16 activations [64][256]
    __shared__ float sred[4][64];      // cross-column-wave partial sums

    const int t    = threadIdx.x;
    const int lane = t & 63;
    const int w    = t >> 6;           // 0..7
    const int wh   = w & 1;            // row half: rows [wh*32, wh*32+32)
    const int wc   = w >> 1;           // 0..3: n-tiles {wc, wc+4, wc+8, wc+12}
    const int p0   = blockIdx.x * MBLK;
    const int lr   = lane & 15;
    const int lq   = lane >> 4;

    const int b0 = p0 / NE;
    const int r0 = p0 - b0 * NE;

    // Column bases for this wave's 4 tiles.
    int nt_[4];
    #pragma unroll
    for (int ti = 0; ti < 4; ++ti) nt_[ti] = (wc + ti * 4) * 16 + lq * 4;

    // ---- Phase A: h1 = silu(E1[e] + F1[b])  -> act (f16) ----
    {
        #pragma unroll
        for (int i = 0; i < 4; ++i) {
            int c   = i * 512 + t;
            int row = c >> 5;
            int c0  = (c & 31) * 8;
            int e = r0 + row;
            int b = b0;
            if (e >= NE) { e -= NE; b += 1; }
            const f4* ep = (const f4*)&E1[e * HID + c0];
            const f4* fp = (const f4*)&F1[b * HID + c0];
            f4 e0 = ep[0], e1 = ep[1];
            f4 f0 = fp[0], f1 = fp[1];
            half8 hv;
            #pragma unroll
            for (int j = 0; j < 4; ++j) hv[j]     = (_Float16)silu_f(e0[j] + f0[j]);
            #pragma unroll
            for (int j = 0; j < 4; ++j) hv[4 + j] = (_Float16)silu_f(e1[j] + f1[j]);
            *(half8*)(act + swz(row, c0 * 2)) = hv;
        }
    }
    __syncthreads();

    f4 acc[4][2];

    // ---- Phase B: h2 = silu(h1 @ mW2 + mb2)  [in-place, bias-folded] ----
    #pragma unroll
    for (int ti = 0; ti < 4; ++ti) {
        f4 bb = *(const f4*)&mb2[nt_[ti]];
        acc[ti][0] = bb; acc[ti][1] = bb;
    }
    mma_phase4<8, 4>(PB2, act, lane, wh, wc, acc);
    __syncthreads();   // all reads of h1 done
    #pragma unroll
    for (int ti = 0; ti < 4; ++ti)
        #pragma unroll
        for (int mt = 0; mt < 2; ++mt) {
            int row = wh * 32 + mt * 16 + lr;
            half4 hv;
            #pragma unroll
            for (int r = 0; r < 4; ++r)
                hv[r] = (_Float16)silu_f(acc[ti][mt][r]);
            *(half4*)(act + swz(row, nt_[ti] * 2)) = hv;
        }
    __syncthreads();   // h2 visible

    // ---- Phase C: g = h2 @ mW3 + mb3 ; invariant  [in-place] ----
    // Tiles: wc, wc+4 (<8: scalar path), wc+8 (norm), wc+12 (norm, iff wc<2).
    #pragma unroll
    for (int ti = 0; ti < 4; ++ti) {
        f4 bb = (ti < 3 || wc < 2) ? *(const f4*)&mb3[nt_[ti]] : (f4){0.f,0.f,0.f,0.f};
        acc[ti][0] = bb; acc[ti][1] = bb;
    }
    if (wc < 2) mma_phase4<8, 4>(PB3, act, lane, wh, wc, acc);
    else        mma_phase4<8, 3>(PB3, act, lane, wh, wc, acc);
    int bmt[2];
    #pragma unroll
    for (int mt = 0; mt < 2; ++mt)
        bmt[mt] = b0 + ((r0 + wh * 32 + mt * 16 + lr) >= NE);
    f4 xh[2][2], sv0[2], sv1[2];
    #pragma unroll
    for (int ti = 0; ti < 2; ++ti)
        #pragma unroll
        for (int mt = 0; mt < 2; ++mt)
            xh[ti][mt] = *(const f4*)&h_abs[bmt[mt] * DIN + nt_[ti]];
    #pragma unroll
    for (int mt = 0; mt < 2; ++mt)
        sv0[mt] = *(const f4*)&S[bmt[mt] * 96 + nt_[0]];    // S idx of tile wc+8 = nt_[2]-128 = nt_[0]
    if (wc < 2) {
        #pragma unroll
        for (int mt = 0; mt < 2; ++mt)
            sv1[mt] = *(const f4*)&S[bmt[mt] * 96 + nt_[1]]; // S idx of tile wc+12 = nt_[1]
    }
    __syncthreads();
    {
        // ti = 0,1: scalar passthrough (tiles < 8, always).
        #pragma unroll
        for (int ti = 0; ti < 2; ++ti)
            #pragma unroll
            for (int mt = 0; mt < 2; ++mt) {
                int row = wh * 32 + mt * 16 + lr;
                half4 hv;
                #pragma unroll
                for (int r = 0; r < 4; ++r)
                    hv[r] = (_Float16)(xh[ti][mt][r] * acc[ti][mt][r]);
                *(half4*)(act + swz(row, nt_[ti] * 2)) = hv;
            }
        // ti = 2: L2-norm path (tiles 8..11, always).
        #pragma unroll
        for (int mt = 0; mt < 2; ++mt) {
            int row = wh * 32 + mt * 16 + lr;
            half4 hv;
            #pragma unroll
            for (int r = 0; r < 4; ++r) {
                float g = acc[2][mt][r];
                hv[r] = (_Float16)__builtin_amdgcn_sqrtf(g * g * sv0[mt][r] + 1e-8f);
            }
            *(half4*)(act + swz(row, nt_[2] * 2)) = hv;
        }
        // ti = 3: L2-norm path (tiles 12,13, iff wc<2).
        if (wc < 2) {
            #pragma unroll
            for (int mt = 0; mt < 2; ++mt) {
                int row = wh * 32 + mt * 16 + lr;
                half4 hv;
                #pragma unroll
                for (int r = 0; r < 4; ++r) {
                    float g = acc[3][mt][r];
                    hv[r] = (_Float16)__builtin_amdgcn_sqrtf(g * g * sv1[mt][r] + 1e-8f);
                }
                *(half4*)(act + swz(row, nt_[3] * 2)) = hv;
            }
        }
    }
    __syncthreads();

    // ---- Phase D: o1 = silu(inv @ oW1[0:224] + Fo[b])  [in-place, Fo-folded] ----
    #pragma unroll
    for (int ti = 0; ti < 4; ++ti)
        #pragma unroll
        for (int mt = 0; mt < 2; ++mt)
            acc[ti][mt] = *(const f4*)&Fo[bmt[mt] * HID + nt_[ti]];
    mma_phase4<7, 4>(PO1, act, lane, wh, wc, acc);
    __syncthreads();
    #pragma unroll
    for (int ti = 0; ti < 4; ++ti)
        #pragma unroll
        for (int mt = 0; mt < 2; ++mt) {
            int row = wh * 32 + mt * 16 + lr;
            half4 hv;
            #pragma unroll
            for (int r = 0; r < 4; ++r)
                hv[r] = (_Float16)silu_f(acc[ti][mt][r]);
            *(half4*)(act + swz(row, nt_[ti] * 2)) = hv;
        }
    __syncthreads();

    // ---- Phase E+F fused: out[p] = silu(o1 @ oW2 + ob2) . oW3 + ob3 ----
    #pragma unroll
    for (int ti = 0; ti < 4; ++ti) {
        f4 bb = *(const f4*)&ob2[nt_[ti]];
        acc[ti][0] = bb; acc[ti][1] = bb;
    }
    mma_phase4<8, 4>(PO2, act, lane, wh, wc, acc);
    {
        float partial[2] = {0.f, 0.f};
        #pragma unroll
        for (int ti = 0; ti < 4; ++ti) {
            f4 wv = *(const f4*)&oW3[nt_[ti]];
            #pragma unroll
            for (int mt = 0; mt < 2; ++mt)
                #pragma unroll
                for (int r = 0; r < 4; ++r)
                    partial[mt] += silu_f(acc[ti][mt][r]) * wv[r];
        }
        #pragma unroll
        for (int mt = 0; mt < 2; ++mt) {
            float s = partial[mt];
            s += __shfl_xor(s, 16, 64);
            s += __shfl_xor(s, 32, 64);
            if (lq == 0) sred[wc][wh * 32 + mt * 16 + lr] = s;
        }
    }
    __syncthreads();
    if (t < 64) {
        float s = ob3[0];
        #pragma unroll
        for (int cc = 0; cc < 4; ++cc) s += sred[cc][t];
        out[p0 + t] = s;
    }
}

extern "C" void kernel_launch(void* const* d_in, const int* in_sizes, int n_in,
                              void* d_out, int out_size, void* d_ws, size_t ws_size,
                              hipStream_t stream) {
    const float* h_abs  = (const float*)d_in[0];
    const float* e_feat = (const float*)d_in[1];
    const float* field  = (const float*)d_in[2];
    const float* mW1 = (const float*)d_in[3];
    const float* mb1 = (const float*)d_in[4];
    const float* mW2 = (const float*)d_in[5];
    const float* mb2 = (const float*)d_in[6];
    const float* mW3 = (const float*)d_in[7];
    const float* mb3 = (const float*)d_in[8];
    const float* oW1 = (const float*)d_in[9];
    const float* ob1 = (const float*)d_in[10];
    const float* oW2 = (const float*)d_in[11];
    const float* ob2 = (const float*)d_in[12];
    const float* oW3 = (const float*)d_in[13];
    const float* ob3 = (const float*)d_in[14];
    float* out = (float*)d_out;

    // Workspace layout
    float* ws = (float*)d_ws;
    float* E1 = ws;                      // 400*256 = 102400 f
    float* F1 = E1 + NE * HID;           // 65536 f
    float* Fo = F1 + BB * HID;           // 65536 f
    float* S  = Fo + BB * HID;           // 24576 f
    _Float16* PB2 = (_Float16*)(S + BB * 96);   // 16*8*64*8 = 65536 h
    _Float16* PB3 = PB2 + 16 * 8 * 64 * 8;      // 14*8*64*8 = 57344 h
    _Float16* PO1 = PB3 + 14 * 8 * 64 * 8;      // 16*7*64*8 = 57344 h
    _Float16* PO2 = PO1 + 16 * 7 * 64 * 8;      // 16*8*64*8 = 65536 h

    precompute_kernel<<<NE + 3 * BB, 256, 0, stream>>>(
        h_abs, e_feat, field, mW1, mb1, oW1, ob1, E1, F1, Fo, S);

    pack_weights<<<480, 64, 0, stream>>>(
        mW2, mW3, oW1, oW2, PB2, PB3, PO1, PO2);

    fused_mfma<<<NBLK, 512, 0, stream>>>(
        h_abs, mb2, mb3, ob2, oW3, ob3,
        E1, F1, Fo, S,
        (const half8*)PB2, (const half8*)PB3, (const half8*)PO1, (const half8*)PO2,
        out);
}

// Round 18
// 94.412 us; speedup vs baseline: 1.3958x; 1.3958x over previous
//
#include <hip/hip_runtime.h>
#include <math.h>

// Problem constants
#define BB 256
#define NE 400
#define NP (BB * NE)        // 102400 pairs
#define HID 256
#define NCOP 224
#define DIN 480
#define MBLK 64             // pairs per block in fused MFMA kernel
#define NBLK (NP / MBLK)    // 1600

typedef _Float16 half8 __attribute__((ext_vector_type(8)));
typedef _Float16 half4 __attribute__((ext_vector_type(4)));
typedef float f4 __attribute__((ext_vector_type(4)));

// Native silu: v_mul + v_exp_f32 + v_add + v_rcp_f32 + v_mul (round 13: -12 us).
static __device__ __forceinline__ float silu_f(float x) {
    float e = __builtin_amdgcn_exp2f(x * -1.44269504088896340736f);
    return x * __builtin_amdgcn_rcpf(1.0f + e);
}

// Swizzled byte offset into one 32 KB activation buffer.
static __device__ __forceinline__ int swz(int row, int colbyte) {
    return (row * 512 + colbyte) ^ ((row & 7) << 4);
}

// ---------------------------------------------------------------------------
// Precompute (fp32): E1/F1/Fo/S as before.
// ---------------------------------------------------------------------------
__global__ void precompute_kernel(const float* __restrict__ h_abs,
                                  const float* __restrict__ e_feat,
                                  const float* __restrict__ field,
                                  const float* __restrict__ mW1,
                                  const float* __restrict__ mb1,
                                  const float* __restrict__ oW1,
                                  const float* __restrict__ ob1,
                                  float* __restrict__ E1,
                                  float* __restrict__ F1,
                                  float* __restrict__ Fo,
                                  float* __restrict__ S)
{
    int r = blockIdx.x;
    int t = threadIdx.x;
    if (r < NE) {
        float a = 0.f;
        #pragma unroll
        for (int k = 0; k < 32; ++k) a += e_feat[r * 32 + k] * mW1[k * HID + t];
        E1[r * HID + t] = a;
    } else if (r < NE + BB) {
        int b = r - NE;
        float a = mb1[t];
        #pragma unroll
        for (int k = 0; k < 64; ++k) a += field[b * 64 + k] * mW1[(32 + k) * HID + t];
        F1[b * HID + t] = a;
    } else if (r < NE + 2 * BB) {
        int b = r - NE - BB;
        float a = ob1[t];
        #pragma unroll
        for (int k = 0; k < 64; ++k) a += field[b * 64 + k] * oW1[(224 + k) * HID + t];
        Fo[b * HID + t] = a;
    } else {
        int b = r - NE - 2 * BB;
        if (t < 64) {
            const float* x = h_abs + b * DIN + 128 + t * 3;
            S[b * 96 + t] = (x[0]*x[0] + x[1]*x[1] + x[2]*x[2]) * (1.0f / 3.0f);
        } else if (t < 96) {
            int c = t - 64;
            const float* x = h_abs + b * DIN + 320 + c * 5;
            float s = 0.f;
            #pragma unroll
            for (int d = 0; d < 5; ++d) s += x[d] * x[d];
            S[b * 96 + t] = s * 0.2f;
        }
    }
}

// ---------------------------------------------------------------------------
// Pack weights (fp32 -> fp16) into MFMA A-operand fragment order.
// ---------------------------------------------------------------------------
__global__ void pack_weights(const float* __restrict__ mW2, const float* __restrict__ mW3,
                             const float* __restrict__ oW1, const float* __restrict__ oW2,
                             _Float16* __restrict__ PB2, _Float16* __restrict__ PB3,
                             _Float16* __restrict__ PO1, _Float16* __restrict__ PO2)
{
    int blk = blockIdx.x;
    int l = threadIdx.x;
    const float* W; _Float16* P; int LD;
    if (blk < 128)      { W = mW2; P = PB2; LD = 256; }
    else if (blk < 240) { blk -= 128; W = mW3; P = PB3; LD = 224; }
    else if (blk < 352) { blk -= 240; W = oW1; P = PO1; LD = 256; }
    else                { blk -= 352; W = oW2; P = PO2; LD = 256; }
    int KST = (P == PO1) ? 7 : 8;
    int nt = blk / KST, ks = blk - nt * KST;
    int n  = nt * 16 + (l & 15);
    int k0 = ks * 32 + (l >> 4) * 8;
    half8 v;
    #pragma unroll
    for (int j = 0; j < 8; ++j) v[j] = (_Float16)W[(size_t)(k0 + j) * LD + n];
    *(half8*)&P[(size_t)(blk * 64 + l) * 8] = v;
}

// ---------------------------------------------------------------------------
// One GEMM phase on the matrix pipe, operands swapped:
//   acc = mfma(W_frag /*A: rows=n*/, act_frag /*B: cols=pair*/, acc)
// Weight fragments hoisted up-front; acc caller-initialized (bias folded).
// ---------------------------------------------------------------------------
template<int KST, bool TWO>
static __device__ __forceinline__ void mma_phase(const half8* __restrict__ Wp,
                                                 const char* actp, int lane,
                                                 int tile0, f4 acc[4][2])
{
    half8 bf0[KST], bf1[TWO ? KST : 1];
    #pragma unroll
    for (int ks = 0; ks < KST; ++ks)
        bf0[ks] = Wp[(tile0 * KST + ks) * 64 + lane];
    if (TWO) {
        #pragma unroll
        for (int ks = 0; ks < KST; ++ks)
            bf1[ks] = Wp[((tile0 + 8) * KST + ks) * 64 + lane];
    }

    #pragma unroll
    for (int ks = 0; ks < KST; ++ks) {
        int kb = ks * 64 + ((lane >> 4) << 4);
        half8 a[4];
        #pragma unroll
        for (int mt = 0; mt < 4; ++mt) {
            int row = mt * 16 + (lane & 15);
            a[mt] = *(const half8*)(actp + ((row * 512 + kb) ^ ((row & 7) << 4)));
        }
        #pragma unroll
        for (int mt = 0; mt < 4; ++mt)
            acc[mt][0] = __builtin_amdgcn_mfma_f32_16x16x32_f16(bf0[ks], a[mt], acc[mt][0], 0, 0, 0);
        if (TWO) {
            #pragma unroll
            for (int mt = 0; mt < 4; ++mt)
                acc[mt][1] = __builtin_amdgcn_mfma_f32_16x16x32_f16(bf1[ks], a[mt], acc[mt][1], 0, 0, 0);
        }
    }
}

// ---------------------------------------------------------------------------
// Fused kernel: 64 pairs / block, 512 threads (8 waves).
// PING-PONG act buffers: one barrier per phase (5 total, was 9). VGPR=84
// caps residency at 2 blocks/CU regardless, so the 2nd buffer is free.
// ---------------------------------------------------------------------------
__global__ __launch_bounds__(512, 1)
void fused_mfma(const float* __restrict__ h_abs,
                const float* __restrict__ mb2, const float* __restrict__ mb3,
                const float* __restrict__ ob2,
                const float* __restrict__ oW3, const float* __restrict__ ob3,
                const float* __restrict__ E1, const float* __restrict__ F1,
                const float* __restrict__ Fo, const float* __restrict__ S,
                const half8* __restrict__ PB2, const half8* __restrict__ PB3,
                const half8* __restrict__ PO1, const half8* __restrict__ PO2,
                float* __restrict__ out)
{
    __shared__ char act[2][MBLK * 512];   // 2 x 32 KB f16 activations
    __shared__ float sred[8][64];         // cross-wave partial sums

    const int t    = threadIdx.x;
    const int lane = t & 63;
    const int w    = t >> 6;           // 0..7
    const int p0   = blockIdx.x * MBLK;
    const int lr   = lane & 15;
    const int lq   = lane >> 4;

    const int b0 = p0 / NE;
    const int r0 = p0 - b0 * NE;

    // Preload all per-column constants once (off the critical path).
    const int nA = w * 16 + lq * 4;          // ntj = 0 (tile w, < 8)
    const int nB = (w + 8) * 16 + lq * 4;    // ntj = 1 (tile w+8)
    f4 bmb2[2], bmb3[2], bob2[2], wv3[2];
    bmb2[0] = *(const f4*)&mb2[nA];  bmb2[1] = *(const f4*)&mb2[nB];
    bmb3[0] = *(const f4*)&mb3[nA];
    bmb3[1] = (w < 6) ? *(const f4*)&mb3[nB] : (f4){0.f, 0.f, 0.f, 0.f};
    bob2[0] = *(const f4*)&ob2[nA];  bob2[1] = *(const f4*)&ob2[nB];
    wv3[0]  = *(const f4*)&oW3[nA];  wv3[1]  = *(const f4*)&oW3[nB];

    // ---- Phase A: h1 = silu(E1[e] + F1[b])  -> act0 ----
    {
        #pragma unroll
        for (int i = 0; i < 4; ++i) {
            int c   = i * 512 + t;
            int row = c >> 5;
            int c0  = (c & 31) * 8;
            int e = r0 + row;
            int b = b0;
            if (e >= NE) { e -= NE; b += 1; }
            const f4* ep = (const f4*)&E1[e * HID + c0];
            const f4* fp = (const f4*)&F1[b * HID + c0];
            f4 e0 = ep[0], e1 = ep[1];
            f4 f0 = fp[0], f1 = fp[1];
            half8 hv;
            #pragma unroll
            for (int j = 0; j < 4; ++j) hv[j]     = (_Float16)silu_f(e0[j] + f0[j]);
            #pragma unroll
            for (int j = 0; j < 4; ++j) hv[4 + j] = (_Float16)silu_f(e1[j] + f1[j]);
            *(half8*)(act[0] + swz(row, c0 * 2)) = hv;
        }
    }
    __syncthreads();   // (1) h1 visible

    f4 acc[4][2];

    // ---- Phase B: h2 = silu(h1 @ mW2 + mb2)   [read act0 -> write act1] ----
    #pragma unroll
    for (int mt = 0; mt < 4; ++mt) { acc[mt][0] = bmb2[0]; acc[mt][1] = bmb2[1]; }
    mma_phase<8, true>(PB2, act[0], lane, w, acc);
    #pragma unroll
    for (int ntj = 0; ntj < 2; ++ntj) {
        int n0 = ntj ? nB : nA;
        #pragma unroll
        for (int mt = 0; mt < 4; ++mt) {
            int row = mt * 16 + lr;
            half4 hv;
            #pragma unroll
            for (int r = 0; r < 4; ++r)
                hv[r] = (_Float16)silu_f(acc[mt][ntj][r]);
            *(half4*)(act[1] + swz(row, n0 * 2)) = hv;
        }
    }
    __syncthreads();   // (2) h2 visible; everyone past B-reads of act0

    // ---- Phase C: g = h2 @ mW3 + mb3 ; invariant  [read act1 -> write act0] ----
    #pragma unroll
    for (int mt = 0; mt < 4; ++mt) { acc[mt][0] = bmb3[0]; acc[mt][1] = bmb3[1]; }
    if (w < 6) mma_phase<8, true >(PB3, act[1], lane, w, acc);
    else       mma_phase<8, false>(PB3, act[1], lane, w, acc);
    int bmt[4];
    #pragma unroll
    for (int mt = 0; mt < 4; ++mt)
        bmt[mt] = b0 + ((r0 + mt * 16 + lr) >= NE);
    f4 xh[4], sv[4], fo[4][2];
    #pragma unroll
    for (int mt = 0; mt < 4; ++mt)
        xh[mt] = *(const f4*)&h_abs[bmt[mt] * DIN + nA];
    if (w < 6) {
        #pragma unroll
        for (int mt = 0; mt < 4; ++mt)
            sv[mt] = *(const f4*)&S[bmt[mt] * 96 + nA];   // S idx for tile w+8 is nB-128 == nA
    }
    // Prefetch phase-D's Fo acc-init here (hides L2 latency under C epilogue).
    #pragma unroll
    for (int mt = 0; mt < 4; ++mt) {
        fo[mt][0] = *(const f4*)&Fo[bmt[mt] * HID + nA];
        fo[mt][1] = *(const f4*)&Fo[bmt[mt] * HID + nB];
    }
    {
        // ntj=0: tile w (<8) -> scalar passthrough path, always.
        #pragma unroll
        for (int mt = 0; mt < 4; ++mt) {
            int row = mt * 16 + lr;
            half4 hv;
            #pragma unroll
            for (int r = 0; r < 4; ++r)
                hv[r] = (_Float16)(xh[mt][r] * acc[mt][0][r]);
            *(half4*)(act[0] + swz(row, nA * 2)) = hv;
        }
        // ntj=1: tile w+8 (exists iff w<6) -> L2-norm path.
        if (w < 6) {
            #pragma unroll
            for (int mt = 0; mt < 4; ++mt) {
                int row = mt * 16 + lr;
                half4 hv;
                #pragma unroll
                for (int r = 0; r < 4; ++r) {
                    float g = acc[mt][1][r];
                    hv[r] = (_Float16)__builtin_amdgcn_sqrtf(g * g * sv[mt][r] + 1e-8f);
                }
                *(half4*)(act[0] + swz(row, nB * 2)) = hv;
            }
        }
    }
    __syncthreads();   // (3) inv visible; everyone past C-reads of act1

    // ---- Phase D: o1 = silu(inv @ oW1[0:224] + Fo[b])  [read act0 -> write act1] ----
    #pragma unroll
    for (int mt = 0; mt < 4; ++mt) { acc[mt][0] = fo[mt][0]; acc[mt][1] = fo[mt][1]; }
    mma_phase<7, true>(PO1, act[0], lane, w, acc);
    #pragma unroll
    for (int ntj = 0; ntj < 2; ++ntj) {
        int n0 = ntj ? nB : nA;
        #pragma unroll
        for (int mt = 0; mt < 4; ++mt) {
            int row = mt * 16 + lr;
            half4 hv;
            #pragma unroll
            for (int r = 0; r < 4; ++r)
                hv[r] = (_Float16)silu_f(acc[mt][ntj][r]);
            *(half4*)(act[1] + swz(row, n0 * 2)) = hv;
        }
    }
    __syncthreads();   // (4) o1 visible

    // ---- Phase E+F fused: out[p] = silu(o1 @ oW2 + ob2) . oW3 + ob3 ----
    #pragma unroll
    for (int mt = 0; mt < 4; ++mt) { acc[mt][0] = bob2[0]; acc[mt][1] = bob2[1]; }
    mma_phase<8, true>(PO2, act[1], lane, w, acc);
    {
        float partial[4] = {0.f, 0.f, 0.f, 0.f};
        #pragma unroll
        for (int ntj = 0; ntj < 2; ++ntj) {
            #pragma unroll
            for (int mt = 0; mt < 4; ++mt)
                #pragma unroll
                for (int r = 0; r < 4; ++r)
                    partial[mt] += silu_f(acc[mt][ntj][r]) * wv3[ntj][r];
        }
        #pragma unroll
        for (int mt = 0; mt < 4; ++mt) {
            float s = partial[mt];
            s += __shfl_xor(s, 16, 64);
            s += __shfl_xor(s, 32, 64);
            if (lq == 0) sred[w][mt * 16 + lr] = s;
        }
    }
    __syncthreads();   // (5) sred visible
    if (t < 64) {
        float s = ob3[0];
        #pragma unroll
        for (int ww = 0; ww < 8; ++ww) s += sred[ww][t];
        out[p0 + t] = s;
    }
}

extern "C" void kernel_launch(void* const* d_in, const int* in_sizes, int n_in,
                              void* d_out, int out_size, void* d_ws, size_t ws_size,
                              hipStream_t stream) {
    const float* h_abs  = (const float*)d_in[0];
    const float* e_feat = (const float*)d_in[1];
    const float* field  = (const float*)d_in[2];
    const float* mW1 = (const float*)d_in[3];
    const float* mb1 = (const float*)d_in[4];
    const float* mW2 = (const float*)d_in[5];
    const float* mb2 = (const float*)d_in[6];
    const float* mW3 = (const float*)d_in[7];
    const float* mb3 = (const float*)d_in[8];
    const float* oW1 = (const float*)d_in[9];
    const float* ob1 = (const float*)d_in[10];
    const float* oW2 = (const float*)d_in[11];
    const float* ob2 = (const float*)d_in[12];
    const float* oW3 = (const float*)d_in[13];
    const float* ob3 = (const float*)d_in[14];
    float* out = (float*)d_out;

    // Workspace layout
    float* ws = (float*)d_ws;
    float* E1 = ws;                      // 400*256 = 102400 f
    float* F1 = E1 + NE * HID;           // 65536 f
    float* Fo = F1 + BB * HID;           // 65536 f
    float* S  = Fo + BB * HID;           // 24576 f
    _Float16* PB2 = (_Float16*)(S + BB * 96);   // 16*8*64*8 = 65536 h
    _Float16* PB3 = PB2 + 16 * 8 * 64 * 8;      // 14*8*64*8 = 57344 h
    _Float16* PO1 = PB3 + 14 * 8 * 64 * 8;      // 16*7*64*8 = 57344 h
    _Float16* PO2 = PO1 + 16 * 7 * 64 * 8;      // 16*8*64*8 = 65536 h

    precompute_kernel<<<NE + 3 * BB, 256, 0, stream>>>(
        h_abs, e_feat, field, mW1, mb1, oW1, ob1, E1, F1, Fo, S);

    pack_weights<<<480, 64, 0, stream>>>(
        mW2, mW3, oW1, oW2, PB2, PB3, PO1, PO2);

    fused_mfma<<<NBLK, 512, 0, stream>>>(
        h_abs, mb2, mb3, ob2, oW3, ob3,
        E1, F1, Fo, S,
        (const half8*)PB2, (const half8*)PB3, (const half8*)PO1, (const half8*)PO2,
        out);
}